// Round 8
// baseline (145.797 us; speedup 1.0000x reference)
//
#include <hip/hip_runtime.h>
#include <hip/hip_bf16.h>
#include <math.h>

// Problem dims (fixed by reference)
#define B_ROWS 8192
#define D_IN   256
#define H1_DIM 512
#define H2_DIM 256
#define D_OUT  64
#define EPSF   1e-12f
#define THRESH 0.9f
// Guard band for hh-only Gram: h=bf16(v), |g - g_hh| <= 2*2^-9 ~ 3.9e-3,
// |fid - fid_hh| <= 7.9e-3. Flag |g_hh| >= 0.94 -> provably catches every
// true edge; flagged pairs get an exact fp32 re-check.
#define GUARD 0.94f

typedef __attribute__((ext_vector_type(8))) short short8;   // 8 bf16 = 4 VGPR
typedef __attribute__((ext_vector_type(4))) float f32x4;

// ---------------- bf16 hi/mid split, fragment-major packing (weights) ----------------
// frag layout (16x16x32 MFMA A/B): tile I, kstep q, lane l, elem e
//   row = I*16 + (l&15), k = q*32 + (l>>4)*8 + e
// flat short index = ((I*(C/32) + q)*64 + lane)*8 + e == t*8 + e
__device__ inline void pack8(const float* __restrict__ src, short* __restrict__ dh,
                             short* __restrict__ dm, int t, int C, int lgq) {
  const int lane = t & 63;
  const int g = t >> 6;
  const int q = g & ((1 << lgq) - 1);
  const int I = g >> lgq;
  const int row = I * 16 + (lane & 15);
  const int k0 = q * 32 + ((lane >> 4) << 3);
  const float* p = src + (size_t)row * C + k0;
  float4 a = *(const float4*)p;
  float4 b = *(const float4*)(p + 4);
  float v[8] = {a.x, a.y, a.z, a.w, b.x, b.y, b.z, b.w};
  short h8[8], m8[8];
#pragma unroll
  for (int e = 0; e < 8; ++e) {
    __hip_bfloat16 h = __float2bfloat16(v[e]);
    float hf = __bfloat162float(h);
    __hip_bfloat16 m = __float2bfloat16(v[e] - hf);
    h8[e] = *(short*)&h;
    m8[e] = *(short*)&m;
  }
  *(short8*)(dh + (size_t)t * 8) = *(short8*)h8;
  *(short8*)(dm + (size_t)t * 8) = *(short8*)m8;
}

__global__ __launch_bounds__(256)
void pack_weights(const float* __restrict__ W1, const float* __restrict__ W2,
                  const float* __restrict__ W3,
                  short* w1h, short* w1m, short* w2h, short* w2m,
                  short* w3h, short* w3m) {
  const int b = blockIdx.x;
  const int tid = threadIdx.x;
  if (b < 64)       pack8(W1, w1h, w1m, b * 256 + tid, 256, 3);
  else if (b < 128) pack8(W2, w2h, w2m, (b - 64) * 256 + tid, 512, 4);
  else              pack8(W3, w3h, w3m, (b - 128) * 256 + tid, 256, 3);
}

// ---------------- fully fused MLP: x -> tanh(L1) -> tanh(L2) -> L3 ----------------
// One block = 64 rows end-to-end (wave w owns i-tile w). Layer1 output never
// leaves the CU: each 32-col chunk c is LDS-transposed into layer2's A-frag
// for kstep c and accumulated into persistent acc2[16]. Software-pipelined
// W staging: stage_w1(c+1) overlaps layer2(c), stage_w2(c+1) overlaps
// layer1(c+1). Epilogue: bias+norms+invn+out(fp32)+normalized-hi vph; zeros res.
__global__ __launch_bounds__(256, 1)
void fused_mlp(const float* __restrict__ x,
               const short* __restrict__ w1h, const short* __restrict__ w1m,
               const short* __restrict__ w2h, const short* __restrict__ w2m,
               const short* __restrict__ w3h, const short* __restrict__ w3m,
               const float* __restrict__ b1, const float* __restrict__ b2,
               const float* __restrict__ b3,
               float* __restrict__ out, short* __restrict__ vph,
               float* __restrict__ invng, float* __restrict__ res) {
  __shared__ __align__(16) short w1s[2 * 2 * 8 * 512];   // 32 KB: chunk's 2 W1 tiles x 8q x hi/mid
  __shared__ __align__(16) short w2s[2 * 16 * 512];      // 32 KB: kstep's 16 W2 tiles x hi/mid
  __shared__ __align__(16) float tb[4][16][36];          // 9 KB: per-wave transpose buffer
  __shared__ float invb[64];

  const int tid = threadIdx.x;
  const int wave = tid >> 6, lane = tid & 63;
  const int rr = lane & 15, gg = lane >> 4;
  const int R0 = blockIdx.x * 64 + wave * 16;            // my i-tile's first row

  // zero this block's 64 res rows (res poisoned 0xAA by harness)
  {
    float4* rz = (float4*)(res + (size_t)blockIdx.x * 64 * 64);
#pragma unroll
    for (int u = 0; u < 4; ++u) rz[u * 256 + tid] = make_float4(0.f, 0.f, 0.f, 0.f);
  }

  // ---- load x directly into layer1 A-frags (hi/mid), no global pack ----
  short8 A1h[8], A1m[8];
#pragma unroll
  for (int q = 0; q < 8; ++q) {
    const float* p = x + (size_t)(R0 + rr) * D_IN + q * 32 + gg * 8;
    float4 a = *(const float4*)p;
    float4 b = *(const float4*)(p + 4);
    float v[8] = {a.x, a.y, a.z, a.w, b.x, b.y, b.z, b.w};
    short h8[8], m8[8];
#pragma unroll
    for (int e = 0; e < 8; ++e) {
      __hip_bfloat16 h = __float2bfloat16(v[e]);
      float hf = __bfloat162float(h);
      __hip_bfloat16 m = __float2bfloat16(v[e] - hf);
      h8[e] = *(short*)&h;
      m8[e] = *(short*)&m;
    }
    A1h[q] = *(short8*)h8;
    A1m[q] = *(short8*)m8;
  }

  auto stage_w1 = [&](int c) {
#pragma unroll
    for (int u = 0; u < 8; ++u) {
      const int item = wave * 8 + u;                     // m*16 + t*8 + q
      const int m = item >> 4, t = (item >> 3) & 1, q = item & 7;
      const short* src = (m ? w1m : w1h) + ((size_t)((2 * c + t) * 8 + q)) * 512 + lane * 8;
      __builtin_amdgcn_global_load_lds(
          (const __attribute__((address_space(1))) void*)src,
          (__attribute__((address_space(3))) void*)(w1s + item * 512), 16, 0, 0);
    }
  };
  auto stage_w2 = [&](int c) {
#pragma unroll
    for (int u = 0; u < 8; ++u) {
      const int item = wave * 8 + u;                     // m*16 + jt
      const int m = item >> 4, jt = item & 15;
      const short* src = (m ? w2m : w2h) + ((size_t)(jt * 16 + c)) * 512 + lane * 8;
      __builtin_amdgcn_global_load_lds(
          (const __attribute__((address_space(1))) void*)src,
          (__attribute__((address_space(3))) void*)(w2s + item * 512), 16, 0, 0);
    }
  };

  f32x4 acc2[16];
#pragma unroll
  for (int j = 0; j < 16; ++j) acc2[j] = (f32x4){0.f, 0.f, 0.f, 0.f};

  stage_w1(0);
  stage_w2(0);
  __syncthreads();

#pragma unroll 1
  for (int c = 0; c < 16; ++c) {
    // ---- layer1: my i-tile x 2 j-tiles (cols 32c..32c+32) ----
    float hv[2][4];
#pragma unroll
    for (int jt = 0; jt < 2; ++jt) {
      f32x4 g = {0.f, 0.f, 0.f, 0.f};
#pragma unroll
      for (int q = 0; q < 8; ++q) {
        short8 Bh = *(const short8*)(w1s + ((jt * 8 + q) << 9) + lane * 8);
        short8 Bm = *(const short8*)(w1s + (((2 + jt) * 8 + q) << 9) + lane * 8);
        g = __builtin_amdgcn_mfma_f32_16x16x32_bf16(A1h[q], Bh, g, 0, 0, 0);
        g = __builtin_amdgcn_mfma_f32_16x16x32_bf16(A1h[q], Bm, g, 0, 0, 0);
        g = __builtin_amdgcn_mfma_f32_16x16x32_bf16(A1m[q], Bh, g, 0, 0, 0);
      }
      const float bv = b1[(2 * c + jt) * 16 + rr];
#pragma unroll
      for (int r = 0; r < 4; ++r) hv[jt][r] = tanhf(g[r] + bv);
    }
#pragma unroll
    for (int jt = 0; jt < 2; ++jt)
#pragma unroll
      for (int r = 0; r < 4; ++r)
        tb[wave][gg * 4 + r][jt * 16 + rr] = hv[jt][r];
    __syncthreads();                     // retire w1s reads; tb visible
    if (c + 1 < 16) stage_w1(c + 1);     // DMA overlaps layer2 below

    // ---- h1 chunk -> layer2 A-frag (kstep c) ----
    short8 A2h, A2m;
    {
      const float* tp = &tb[wave][rr][gg * 8];
      float4 a = *(const float4*)tp;
      float4 b = *(const float4*)(tp + 4);
      float v[8] = {a.x, a.y, a.z, a.w, b.x, b.y, b.z, b.w};
      short h8[8], m8[8];
#pragma unroll
      for (int e = 0; e < 8; ++e) {
        __hip_bfloat16 h = __float2bfloat16(v[e]);
        float hf = __bfloat162float(h);
        __hip_bfloat16 m = __float2bfloat16(v[e] - hf);
        h8[e] = *(short*)&h;
        m8[e] = *(short*)&m;
      }
      A2h = *(short8*)h8;
      A2m = *(short8*)m8;
    }
    // ---- layer2 partial accumulation (kstep c) ----
#pragma unroll
    for (int jt2 = 0; jt2 < 16; ++jt2) {
      short8 Bh = *(const short8*)(w2s + (jt2 << 9) + lane * 8);
      short8 Bm = *(const short8*)(w2s + ((16 + jt2) << 9) + lane * 8);
      acc2[jt2] = __builtin_amdgcn_mfma_f32_16x16x32_bf16(A2h, Bh, acc2[jt2], 0, 0, 0);
      acc2[jt2] = __builtin_amdgcn_mfma_f32_16x16x32_bf16(A2h, Bm, acc2[jt2], 0, 0, 0);
      acc2[jt2] = __builtin_amdgcn_mfma_f32_16x16x32_bf16(A2m, Bh, acc2[jt2], 0, 0, 0);
    }
    __syncthreads();                     // retire w2s reads; drain w1 DMA
    if (c + 1 < 16) stage_w2(c + 1);     // DMA overlaps next layer1
  }

  // ---- stage W3 (4 tiles x 8q x hi/mid = 64 KB) into w1s|w2s ----
#pragma unroll
  for (int u = 0; u < 16; ++u) {
    const int item = wave * 16 + u;                      // m*32 + t*8 + q
    const int m = item >> 5, rest = item & 31;
    const short* src = (m ? w3m : w3h) + ((size_t)rest) * 512 + lane * 8;
    short* dst = (item < 32) ? (w1s + item * 512) : (w2s + (item - 32) * 512);
    __builtin_amdgcn_global_load_lds(
        (const __attribute__((address_space(1))) void*)src,
        (__attribute__((address_space(3))) void*)dst, 16, 0, 0);
  }

  // ---- h2 (acc2) -> layer3 A-frags (tanh + split) via tb ----
  short8 A3h[8], A3m[8];
#pragma unroll
  for (int q3 = 0; q3 < 8; ++q3) {
#pragma unroll
    for (int jt = 0; jt < 2; ++jt) {
      const int jt2 = q3 * 2 + jt;
      const float bv = b2[jt2 * 16 + rr];
#pragma unroll
      for (int r = 0; r < 4; ++r)
        tb[wave][gg * 4 + r][jt * 16 + rr] = tanhf(acc2[jt2][r] + bv);
    }
    __syncthreads();
    {
      const float* tp = &tb[wave][rr][gg * 8];
      float4 a = *(const float4*)tp;
      float4 b = *(const float4*)(tp + 4);
      float v[8] = {a.x, a.y, a.z, a.w, b.x, b.y, b.z, b.w};
      short h8[8], m8[8];
#pragma unroll
      for (int e = 0; e < 8; ++e) {
        __hip_bfloat16 h = __float2bfloat16(v[e]);
        float hf = __bfloat162float(h);
        __hip_bfloat16 m = __float2bfloat16(v[e] - hf);
        h8[e] = *(short*)&h;
        m8[e] = *(short*)&m;
      }
      A3h[q3] = *(short8*)h8;
      A3m[q3] = *(short8*)m8;
    }
    __syncthreads();
  }

  // ---- layer3 ----
  f32x4 acc3[4];
#pragma unroll
  for (int t = 0; t < 4; ++t) acc3[t] = (f32x4){0.f, 0.f, 0.f, 0.f};
#pragma unroll
  for (int q3 = 0; q3 < 8; ++q3)
#pragma unroll
    for (int t = 0; t < 4; ++t) {
      short8 Bh = *(const short8*)(w1s + ((t * 8 + q3) << 9) + lane * 8);
      short8 Bm = *(const short8*)(w2s + ((t * 8 + q3) << 9) + lane * 8);
      acc3[t] = __builtin_amdgcn_mfma_f32_16x16x32_bf16(A3h[q3], Bh, acc3[t], 0, 0, 0);
      acc3[t] = __builtin_amdgcn_mfma_f32_16x16x32_bf16(A3h[q3], Bm, acc3[t], 0, 0, 0);
      acc3[t] = __builtin_amdgcn_mfma_f32_16x16x32_bf16(A3m[q3], Bh, acc3[t], 0, 0, 0);
    }

  // ---- epilogue: bias, out, norms/invn, normalized-hi vph ----
  float val[4][4];
#pragma unroll
  for (int t = 0; t < 4; ++t) {
    const float bv = b3[t * 16 + rr];
#pragma unroll
    for (int r = 0; r < 4; ++r) val[t][r] = acc3[t][r] + bv;
  }
#pragma unroll
  for (int t = 0; t < 4; ++t)
#pragma unroll
    for (int r = 0; r < 4; ++r)
      out[(size_t)(R0 + gg * 4 + r) * D_OUT + t * 16 + rr] = val[t][r];
#pragma unroll
  for (int r = 0; r < 4; ++r) {
    float sq = 0.f;
#pragma unroll
    for (int t = 0; t < 4; ++t) sq = fmaf(val[t][r], val[t][r], sq);
#pragma unroll
    for (int m = 1; m < 16; m <<= 1) sq += __shfl_xor(sq, m, 64);
    if (rr == 0) {
      const float iv = 1.0f / (sqrtf(sq) + EPSF);
      invb[wave * 16 + gg * 4 + r] = iv;
      invng[R0 + gg * 4 + r] = iv;
    }
  }
  __syncthreads();
  const int ItG = blockIdx.x * 4 + wave;
#pragma unroll
  for (int q = 0; q < 2; ++q) {
#pragma unroll
    for (int jt = 0; jt < 2; ++jt)
#pragma unroll
      for (int r = 0; r < 4; ++r)
        tb[wave][gg * 4 + r][jt * 16 + rr] = val[2 * q + jt][r];
    __syncthreads();
    {
      const float* tp = &tb[wave][rr][gg * 8];
      float4 a = *(const float4*)tp;
      float4 b = *(const float4*)(tp + 4);
      const float sc = invb[wave * 16 + rr];
      float v[8] = {a.x, a.y, a.z, a.w, b.x, b.y, b.z, b.w};
      short h8[8];
#pragma unroll
      for (int e = 0; e < 8; ++e) {
        __hip_bfloat16 h = __float2bfloat16(v[e] * sc);
        h8[e] = *(short*)&h;
      }
      *(short8*)(vph + ((size_t)(ItG * 2 + q) * 64 + lane) * 8) = *(short8*)h8;
    }
    __syncthreads();
  }
}

// ---------------- MFMA Gram (hh-only) + guard-band + exact recheck ----------------
#define JSPLIT 8
#define CT 8                                 // j-tiles per chunk (128 j-rows)
#define NCHUNK (B_ROWS / JSPLIT / 16 / CT)   // 8

__global__ __launch_bounds__(256, 2)
void gram_accum(const short* __restrict__ vph, const float* __restrict__ out,
                const float* __restrict__ invn, float* __restrict__ res) {
  __shared__ __align__(16) short lh[2][CT * 1024];   // 2 x 16 KB (hi only)
  const int tid = threadIdx.x;
  const int wave = tid >> 6;
  const int lane = tid & 63;
  const int i0 = blockIdx.x * 128;                   // 8 i-tiles per block
  const int jbase = blockIdx.y * (B_ROWS / JSPLIT);  // 1024 j-rows

  short8 Ah[8][2];
#pragma unroll
  for (int it = 0; it < 8; ++it) {
    const int It = (i0 >> 4) + it;
#pragma unroll
    for (int q = 0; q < 2; ++q)
      Ah[it][q] = *(const short8*)(vph + (size_t)It * 1024 + q * 512 + lane * 8);
  }

  auto stage = [&](int c, int bf) {
    const size_t base = ((size_t)(jbase >> 4) + c * CT) * 1024;
#pragma unroll
    for (int u = 0; u < 4; ++u) {
      const int item = wave * 4 + u;   // 0..15, wave-uniform
      const short* src = vph + base + item * 512;
      short* dst = lh[bf] + item * 512;
      __builtin_amdgcn_global_load_lds(
          (const __attribute__((address_space(1))) void*)(src + lane * 8),
          (__attribute__((address_space(3))) void*)dst, 16, 0, 0);
    }
  };

  stage(0, 0);
  for (int c = 0; c < NCHUNK; ++c) {
    __syncthreads();
    if (c + 1 < NCHUNK) stage(c + 1, (c + 1) & 1);
    const int bf = c & 1;
#pragma unroll
    for (int t = 0; t < 2; ++t) {
      const int jt = wave * 2 + t;
      const int j0 = jbase + (c * CT + jt) * 16;
      short8 Bh0 = *(const short8*)(lh[bf] + jt * 1024 + lane * 8);
      short8 Bh1 = *(const short8*)(lh[bf] + jt * 1024 + 512 + lane * 8);
      f32x4 g[8];
#pragma unroll
      for (int it = 0; it < 8; ++it) g[it] = (f32x4){0.f, 0.f, 0.f, 0.f};
#pragma unroll
      for (int it = 0; it < 8; ++it) g[it] = __builtin_amdgcn_mfma_f32_16x16x32_bf16(Ah[it][0], Bh0, g[it], 0, 0, 0);
#pragma unroll
      for (int it = 0; it < 8; ++it) g[it] = __builtin_amdgcn_mfma_f32_16x16x32_bf16(Ah[it][1], Bh1, g[it], 0, 0, 0);
#pragma unroll
      for (int it = 0; it < 8; ++it) {
        const float m01 = fmaxf(fabsf(g[it][0]), fabsf(g[it][1]));
        const float m23 = fmaxf(fabsf(g[it][2]), fabsf(g[it][3]));
        if (fmaxf(m01, m23) >= GUARD) {
          const int j = j0 + (lane & 15);
          const float ivj = invn[j];
          const float* __restrict__ oj = out + (size_t)j * D_OUT;
#pragma unroll
          for (int r = 0; r < 4; ++r) {
            if (fabsf(g[it][r]) >= GUARD) {
              const int i = i0 + it * 16 + (lane >> 4) * 4 + r;
              if (i != j) {
                const float* __restrict__ oi = out + (size_t)i * D_OUT;
                float d = 0.f;
                for (int k = 0; k < D_OUT; k += 4) {
                  float4 a = *(const float4*)(oi + k);
                  float4 b = *(const float4*)(oj + k);
                  d = fmaf(a.x, b.x, d); d = fmaf(a.y, b.y, d);
                  d = fmaf(a.z, b.z, d); d = fmaf(a.w, b.w, d);
                }
                const float nd = d * invn[i] * ivj;
                if (nd * nd >= THRESH) {
                  float* __restrict__ ri = res + (size_t)i * D_OUT;
                  for (int k = 0; k < D_OUT; ++k) atomicAdd(&ri[k], oj[k]);
                }
              }
            }
          }
        }
      }
    }
  }
}

// ---------------- launch ----------------
#define MB (1024 * 1024)

extern "C" void kernel_launch(void* const* d_in, const int* in_sizes, int n_in,
                              void* d_out, int out_size, void* d_ws, size_t ws_size,
                              hipStream_t stream) {
  const float* x  = (const float*)d_in[0];
  const float* W1 = (const float*)d_in[1];
  const float* b1 = (const float*)d_in[2];
  const float* W2 = (const float*)d_in[3];
  const float* b2 = (const float*)d_in[4];
  const float* W3 = (const float*)d_in[5];
  const float* b3 = (const float*)d_in[6];
  float* res = (float*)d_out;

  char* ws = (char*)d_ws;
  float* out  = (float*)(ws + 8 * MB);
  short* vph  = (short*)(ws + 11 * MB);
  float* invn = (float*)(ws + 12 * MB);
  short* w1h = (short*)(ws + 24 * MB);
  short* w1m = (short*)(ws + 24 * MB + 256 * 1024);
  short* w2h = (short*)(ws + 24 * MB + 512 * 1024);
  short* w2m = (short*)(ws + 24 * MB + 768 * 1024);
  short* w3h = (short*)(ws + 25 * MB);
  short* w3m = (short*)(ws + 25 * MB + 32 * 1024);

  pack_weights<<<136, 256, 0, stream>>>(W1, W2, W3, w1h, w1m, w2h, w2m, w3h, w3m);
  fused_mlp<<<B_ROWS / 64, 256, 0, stream>>>(
      x, w1h, w1m, w2h, w2m, w3h, w3m, b1, b2, b3, out, vph, invn, res);
  gram_accum<<<dim3(B_ROWS / 128, JSPLIT), 256, 0, stream>>>(vph, out, invn, res);
}

// Round 9
// 139.873 us; speedup vs baseline: 1.0424x; 1.0424x over previous
//
#include <hip/hip_runtime.h>
#include <hip/hip_bf16.h>
#include <math.h>

// Problem dims (fixed by reference)
#define B_ROWS 8192
#define D_IN   256
#define H1_DIM 512
#define H2_DIM 256
#define D_OUT  64
#define EPSF   1e-12f
#define THRESH 0.9f
// Guard band for hh-only Gram: h=bf16(v), |g - g_hh| <= 2*2^-9 ~ 3.9e-3,
// |fid - fid_hh| <= 7.9e-3. Flag |g_hh| >= 0.94 -> provably catches every
// true edge; flagged pairs get an exact fp32 re-check.
#define GUARD 0.94f

typedef __attribute__((ext_vector_type(8))) short short8;   // 8 bf16 = 4 VGPR
typedef __attribute__((ext_vector_type(4))) float f32x4;

// ---------------- MFMA GEMM: C[M,N] = act(A[M,K] @ B[N,K]^T + bias) ----------------
// 64-row x (32*JT)-col blocks, 4 waves (2x2), wave = 2 i-tiles x JT j-tiles.
// Raw fp32 operands (x, W1/W2/W3) are converted to bf16 hi/mid fragments
// IN-REGISTER during staging (global load -> split -> ds_write), eliminating
// all pre-pack kernels. Packed intermediates (h1,h2) use global_load_lds DMA.
// Split product: AhBh + AhBm + AmBh (dropped term <= 2^-18 relative).
// MODE 1: tanh + split-pack (hi+mid) epilogue for the next gemm.
// MODE 2: final layer — zero `rz`, write fp32 Cout, row norms in-block,
//         export invn[], write NORMALIZED hi-only pack dh (= vph for gram).
template<int KSTEPS, int JT, int MODE, bool ARAW>
__global__ __launch_bounds__(256, 2)
void mfma_gemm(const float* __restrict__ Araw,
               const short* __restrict__ pAh, const short* __restrict__ pAm,
               const float* __restrict__ Braw,
               const float* __restrict__ bias, float* __restrict__ Cout,
               short* __restrict__ dh, short* __restrict__ dm, int N,
               float* __restrict__ rz, float* __restrict__ invng) {
  constexpr int K = KSTEPS * 32;
  constexpr int ITB = 4;                   // i-tiles per block (64 rows)
  constexpr int BTJ = 2 * JT;              // B tiles per block
  constexpr int BPW = JT / 2;              // raw B tiles per wave (1 or 2)
  constexpr int WCOL = 16 * JT + 4;        // padded wbuf row stride
  union SM {
    struct {
      short Ah[2][ITB * 512];
      short Am[2][ITB * 512];
      short Bh[2][BTJ * 512];
      short Bm[2][BTJ * 512];
    } st;
    float wbuf[4 * 32 * WCOL];
  };
  __shared__ __align__(16) SM sm;
  __shared__ float nsum[2][64];
  __shared__ float invb[64];

  const int tid = threadIdx.x;
  const int wave = tid >> 6, lane = tid & 63;
  const int wi = wave >> 1, wj = wave & 1;
  const int rr = lane & 15, gg = lane >> 4;
  const int bIt0 = blockIdx.x * ITB;
  const int bJt0 = blockIdx.y * BTJ;

  if constexpr (MODE == 2) {
    // zero the 64 res rows this block owns (res poisoned 0xAA by harness)
    float4* rz4 = (float4*)(rz + (size_t)blockIdx.x * 64 * 64);
#pragma unroll
    for (int u = 0; u < 4; ++u)
      rz4[u * 256 + tid] = make_float4(0.f, 0.f, 0.f, 0.f);
  }

  // register staging buffers for raw operands
  float ar[8];
  float br[BPW][8];

  auto gload8 = [&](const float* __restrict__ p, float* r) {
    float4 a = *(const float4*)p;
    float4 b = *(const float4*)(p + 4);
    r[0] = a.x; r[1] = a.y; r[2] = a.z; r[3] = a.w;
    r[4] = b.x; r[5] = b.y; r[6] = b.z; r[7] = b.w;
  };

  auto loads = [&](int q) {
    if constexpr (ARAW)
      gload8(Araw + (size_t)((bIt0 + wave) * 16 + rr) * K + q * 32 + gg * 8, ar);
#pragma unroll
    for (int u = 0; u < BPW; ++u)
      gload8(Braw + (size_t)((bJt0 + wave * BPW + u) * 16 + rr) * K + q * 32 + gg * 8, br[u]);
  };

  auto stageA = [&](int q, int bf) {   // packed A via DMA (when !ARAW)
#pragma unroll
    for (int u = 0; u < 2; ++u) {
      const int item = wave * 2 + u;   // wave-uniform: tile t, half m
      const int t = item >> 1, m = item & 1;
      const short* src = (m ? pAm : pAh) + ((size_t)(bIt0 + t) * KSTEPS + q) * 512;
      short* dst = (m ? sm.st.Am : sm.st.Ah)[bf] + t * 512;
      __builtin_amdgcn_global_load_lds(
          (const __attribute__((address_space(1))) void*)(src + lane * 8),
          (__attribute__((address_space(3))) void*)dst, 16, 0, 0);
    }
  };

  auto split_write = [&](const float* r, short* dsth, short* dstm) {
    short h8[8], m8[8];
#pragma unroll
    for (int e = 0; e < 8; ++e) {
      __hip_bfloat16 h = __float2bfloat16(r[e]);
      float hf = __bfloat162float(h);
      __hip_bfloat16 m = __float2bfloat16(r[e] - hf);
      h8[e] = *(short*)&h;
      m8[e] = *(short*)&m;
    }
    *(short8*)(dsth + lane * 8) = *(short8*)h8;
    *(short8*)(dstm + lane * 8) = *(short8*)m8;
  };

  auto cvt_write = [&](int bf) {
    if constexpr (ARAW)
      split_write(ar, sm.st.Ah[bf] + wave * 512, sm.st.Am[bf] + wave * 512);
#pragma unroll
    for (int u = 0; u < BPW; ++u)
      split_write(br[u], sm.st.Bh[bf] + (wave * BPW + u) * 512,
                         sm.st.Bm[bf] + (wave * BPW + u) * 512);
  };

  f32x4 acc[2][JT];
#pragma unroll
  for (int a = 0; a < 2; ++a)
#pragma unroll
    for (int b = 0; b < JT; ++b) acc[a][b] = (f32x4){0.f, 0.f, 0.f, 0.f};

  loads(0);
  if constexpr (!ARAW) stageA(0, 0);
  cvt_write(0);
  for (int q = 0; q < KSTEPS; ++q) {
    __syncthreads();                       // buf q visible (ds_writes + DMA drained)
    const int bf = q & 1, nbf = (q + 1) & 1;
    if (q + 1 < KSTEPS) {
      loads(q + 1);                        // global loads in flight over compute
      if constexpr (!ARAW) stageA(q + 1, nbf);
    }
    short8 Ah[2], Am[2];
#pragma unroll
    for (int it = 0; it < 2; ++it) {
      Ah[it] = *(const short8*)(sm.st.Ah[bf] + (wi * 2 + it) * 512 + lane * 8);
      Am[it] = *(const short8*)(sm.st.Am[bf] + (wi * 2 + it) * 512 + lane * 8);
    }
    short8 Bh[JT], Bm[JT];
#pragma unroll
    for (int jt = 0; jt < JT; ++jt) {
      Bh[jt] = *(const short8*)(sm.st.Bh[bf] + (wj * JT + jt) * 512 + lane * 8);
      Bm[jt] = *(const short8*)(sm.st.Bm[bf] + (wj * JT + jt) * 512 + lane * 8);
    }
#pragma unroll
    for (int it = 0; it < 2; ++it)
#pragma unroll
      for (int jt = 0; jt < JT; ++jt) {
        acc[it][jt] = __builtin_amdgcn_mfma_f32_16x16x32_bf16(Ah[it], Bh[jt], acc[it][jt], 0, 0, 0);
        acc[it][jt] = __builtin_amdgcn_mfma_f32_16x16x32_bf16(Ah[it], Bm[jt], acc[it][jt], 0, 0, 0);
        acc[it][jt] = __builtin_amdgcn_mfma_f32_16x16x32_bf16(Am[it], Bh[jt], acc[it][jt], 0, 0, 0);
      }
    if (q + 1 < KSTEPS) cvt_write(nbf);    // after compute: loads' latency covered
  }
  __syncthreads();   // staging dead; union region becomes wbuf

  float bv[JT];
#pragma unroll
  for (int jt = 0; jt < JT; ++jt)
    bv[jt] = bias[(bJt0 + wj * JT + jt) * 16 + rr];

  // C/D layout: col = lane&15, row = (lane>>4)*4 + r
  if constexpr (MODE == 1) {
#pragma unroll
    for (int it = 0; it < 2; ++it)
#pragma unroll
      for (int jt = 0; jt < JT; ++jt)
#pragma unroll
        for (int r = 0; r < 4; ++r) {
          const float val = tanhf(acc[it][jt][r] + bv[jt]);
          const int row_l = it * 16 + gg * 4 + r;
          const int col_l = jt * 16 + rr;
          sm.wbuf[(wave * 32 + row_l) * WCOL + col_l] = val;
        }
    __syncthreads();
  } else {
#pragma unroll
    for (int it = 0; it < 2; ++it)
#pragma unroll
      for (int r = 0; r < 4; ++r) {
        float sq = 0.f;
        const int row_l = it * 16 + gg * 4 + r;
#pragma unroll
        for (int jt = 0; jt < JT; ++jt) {
          const float val = acc[it][jt][r] + bv[jt];
          const int col_l = jt * 16 + rr;
          sm.wbuf[(wave * 32 + row_l) * WCOL + col_l] = val;
          const int row = (bIt0 + wi * 2 + it) * 16 + gg * 4 + r;
          Cout[(size_t)row * N + wj * (16 * JT) + col_l] = val;
          sq = fmaf(val, val, sq);
        }
#pragma unroll
        for (int m = 1; m < 16; m <<= 1) sq += __shfl_xor(sq, m, 64);
        if (rr == 0) nsum[wj][wi * 32 + row_l] = sq;
      }
    __syncthreads();
    if (tid < 64) {
      const float iv = 1.0f / (sqrtf(nsum[0][tid] + nsum[1][tid]) + EPSF);
      invb[tid] = iv;
      invng[blockIdx.x * 64 + tid] = iv;
    }
    __syncthreads();
  }

  // pack epilogue: wbuf -> fragment-major (MODE 1: hi+mid; MODE 2: normalized hi)
  constexpr int QLMAX = (JT >= 2) ? (JT / 2) : 1;
#pragma unroll
  for (int itl = 0; itl < 2; ++itl)
#pragma unroll
    for (int ql = 0; ql < QLMAX; ++ql) {
      const int row_l = itl * 16 + rr;                   // [0,32)
      const int kl = ql * 32 + gg * 8;
      const float* wp = &sm.wbuf[(wave * 32 + row_l) * WCOL + kl];
      const float scale = (MODE == 2) ? invb[wi * 32 + row_l] : 1.0f;
      float4 a = *(const float4*)wp;
      float4 b = *(const float4*)(wp + 4);
      float v[8] = {a.x, a.y, a.z, a.w, b.x, b.y, b.z, b.w};
      short h8[8], m8[8];
#pragma unroll
      for (int e = 0; e < 8; ++e) {
        const float sv = v[e] * scale;
        __hip_bfloat16 h = __float2bfloat16(sv);
        h8[e] = *(short*)&h;
        if constexpr (MODE == 1) {
          float hf = __bfloat162float(h);
          __hip_bfloat16 m = __float2bfloat16(sv - hf);
          m8[e] = *(short*)&m;
        }
      }
      const int ItG = bIt0 + wi * 2 + itl;
      const int qG = (((bJt0 + wj * JT) * 16) + ql * 32) >> 5;
      const size_t off = ((size_t)(ItG * (N >> 5) + qG) * 64 + lane) * 8;
      *(short8*)(dh + off) = *(short8*)h8;
      if constexpr (MODE == 1) *(short8*)(dm + off) = *(short8*)m8;
    }
}

// ---------------- MFMA Gram (hh-only) + guard-band + exact recheck ----------------
#define JSPLIT 8
#define CT 8                                 // j-tiles per chunk (128 j-rows)
#define NCHUNK (B_ROWS / JSPLIT / 16 / CT)   // 8

__global__ __launch_bounds__(256, 2)
void gram_accum(const short* __restrict__ vph, const float* __restrict__ out,
                const float* __restrict__ invn, float* __restrict__ res) {
  __shared__ __align__(16) short lh[2][CT * 1024];   // 2 x 16 KB (hi only)
  const int tid = threadIdx.x;
  const int wave = tid >> 6;
  const int lane = tid & 63;
  const int i0 = blockIdx.x * 128;                   // 8 i-tiles per block
  const int jbase = blockIdx.y * (B_ROWS / JSPLIT);  // 1024 j-rows

  short8 Ah[8][2];
#pragma unroll
  for (int it = 0; it < 8; ++it) {
    const int It = (i0 >> 4) + it;
#pragma unroll
    for (int q = 0; q < 2; ++q)
      Ah[it][q] = *(const short8*)(vph + (size_t)It * 1024 + q * 512 + lane * 8);
  }

  auto stage = [&](int c, int bf) {
    const size_t base = ((size_t)(jbase >> 4) + c * CT) * 1024;
#pragma unroll
    for (int u = 0; u < 4; ++u) {
      const int item = wave * 4 + u;   // 0..15, wave-uniform
      const short* src = vph + base + item * 512;
      short* dst = lh[bf] + item * 512;
      __builtin_amdgcn_global_load_lds(
          (const __attribute__((address_space(1))) void*)(src + lane * 8),
          (__attribute__((address_space(3))) void*)dst, 16, 0, 0);
    }
  };

  stage(0, 0);
  for (int c = 0; c < NCHUNK; ++c) {
    __syncthreads();
    if (c + 1 < NCHUNK) stage(c + 1, (c + 1) & 1);
    const int bf = c & 1;
#pragma unroll
    for (int t = 0; t < 2; ++t) {
      const int jt = wave * 2 + t;
      const int j0 = jbase + (c * CT + jt) * 16;
      short8 Bh0 = *(const short8*)(lh[bf] + jt * 1024 + lane * 8);
      short8 Bh1 = *(const short8*)(lh[bf] + jt * 1024 + 512 + lane * 8);
      f32x4 g[8];
#pragma unroll
      for (int it = 0; it < 8; ++it) g[it] = (f32x4){0.f, 0.f, 0.f, 0.f};
#pragma unroll
      for (int it = 0; it < 8; ++it) g[it] = __builtin_amdgcn_mfma_f32_16x16x32_bf16(Ah[it][0], Bh0, g[it], 0, 0, 0);
#pragma unroll
      for (int it = 0; it < 8; ++it) g[it] = __builtin_amdgcn_mfma_f32_16x16x32_bf16(Ah[it][1], Bh1, g[it], 0, 0, 0);
#pragma unroll
      for (int it = 0; it < 8; ++it) {
        const float m01 = fmaxf(fabsf(g[it][0]), fabsf(g[it][1]));
        const float m23 = fmaxf(fabsf(g[it][2]), fabsf(g[it][3]));
        if (fmaxf(m01, m23) >= GUARD) {
          const int j = j0 + (lane & 15);
          const float ivj = invn[j];
          const float* __restrict__ oj = out + (size_t)j * D_OUT;
#pragma unroll
          for (int r = 0; r < 4; ++r) {
            if (fabsf(g[it][r]) >= GUARD) {
              const int i = i0 + it * 16 + (lane >> 4) * 4 + r;
              if (i != j) {
                const float* __restrict__ oi = out + (size_t)i * D_OUT;
                float d = 0.f;
                for (int k = 0; k < D_OUT; k += 4) {
                  float4 a = *(const float4*)(oi + k);
                  float4 b = *(const float4*)(oj + k);
                  d = fmaf(a.x, b.x, d); d = fmaf(a.y, b.y, d);
                  d = fmaf(a.z, b.z, d); d = fmaf(a.w, b.w, d);
                }
                const float nd = d * invn[i] * ivj;
                if (nd * nd >= THRESH) {
                  float* __restrict__ ri = res + (size_t)i * D_OUT;
                  for (int k = 0; k < D_OUT; ++k) atomicAdd(&ri[k], oj[k]);
                }
              }
            }
          }
        }
      }
    }
  }
}

// ---------------- launch ----------------
#define MB (1024 * 1024)

extern "C" void kernel_launch(void* const* d_in, const int* in_sizes, int n_in,
                              void* d_out, int out_size, void* d_ws, size_t ws_size,
                              hipStream_t stream) {
  const float* x  = (const float*)d_in[0];
  const float* W1 = (const float*)d_in[1];
  const float* b1 = (const float*)d_in[2];
  const float* W2 = (const float*)d_in[3];
  const float* b2 = (const float*)d_in[4];
  const float* W3 = (const float*)d_in[5];
  const float* b3 = (const float*)d_in[6];
  float* res = (float*)d_out;

  char* ws = (char*)d_ws;
  // h2h/h2m at [0,8) MB; h1h/h1m at [8,24) MB; out/vph/invn reuse [8,16)
  // after h1 is dead (consumed by gemm2).
  short* h2h = (short*)(ws + 0 * MB);
  short* h2m = (short*)(ws + 4 * MB);
  short* h1h = (short*)(ws + 8 * MB);
  short* h1m = (short*)(ws + 16 * MB);
  float* out  = (float*)(ws + 8 * MB);
  short* vph  = (short*)(ws + 11 * MB);
  float* invn = (float*)(ws + 12 * MB);

  // gemm1: [8192,256](raw x) @ W1^T(raw) -> tanh -> packed h1 (N=512)
  mfma_gemm<8, 4, 1, true><<<dim3(128, 4), 256, 0, stream>>>(
      x, nullptr, nullptr, W1, b1, nullptr, h1h, h1m, H1_DIM, nullptr, nullptr);
  // gemm2: packed h1 @ W2^T(raw) -> tanh -> packed h2 (N=256)
  mfma_gemm<16, 2, 1, false><<<dim3(128, 4), 256, 0, stream>>>(
      nullptr, h1h, h1m, W2, b2, nullptr, h2h, h2m, H2_DIM, nullptr, nullptr);
  // gemm3: packed h2 @ W3^T(raw) + b -> fp32 out + invn + normalized hi pack; zeros res
  mfma_gemm<8, 2, 2, false><<<dim3(128, 1), 256, 0, stream>>>(
      nullptr, h2h, h2m, W3, b3, out, vph, nullptr, D_OUT, res, invn);
  gram_accum<<<dim3(B_ROWS / 128, JSPLIT), 256, 0, stream>>>(vph, out, invn, res);
}

// Round 10
// 136.486 us; speedup vs baseline: 1.0682x; 1.0248x over previous
//
#include <hip/hip_runtime.h>
#include <hip/hip_bf16.h>
#include <math.h>

// Problem dims (fixed by reference)
#define B_ROWS 8192
#define D_IN   256
#define H1_DIM 512
#define H2_DIM 256
#define D_OUT  64
#define EPSF   1e-12f
#define THRESH 0.9f
// Guard band for hh-only Gram: h=bf16(v), |g - g_hh| <= 2*2^-9 ~ 3.9e-3,
// |fid - fid_hh| <= 7.9e-3. Flag |g_hh| >= 0.94 -> provably catches every
// true edge; flagged pairs get an exact fp32 re-check.
#define GUARD 0.94f

typedef __attribute__((ext_vector_type(8))) short short8;   // 8 bf16 = 4 VGPR
typedef __attribute__((ext_vector_type(4))) float f32x4;

// ---------------- bf16 hi/mid split, fragment-major packing (weights only) ----------------
// frag layout (16x16x32 MFMA A/B): tile I, kstep q, lane l, elem e
//   row = I*16 + (l&15), k = q*32 + (l>>4)*8 + e
__device__ inline void pack8(const float* __restrict__ src, short* __restrict__ dh,
                             short* __restrict__ dm, int t, int C, int lgq) {
  const int lane = t & 63;
  const int g = t >> 6;
  const int q = g & ((1 << lgq) - 1);
  const int I = g >> lgq;
  const int row = I * 16 + (lane & 15);
  const int k0 = q * 32 + ((lane >> 4) << 3);
  const float* p = src + (size_t)row * C + k0;
  float4 a = *(const float4*)p;
  float4 b = *(const float4*)(p + 4);
  float v[8] = {a.x, a.y, a.z, a.w, b.x, b.y, b.z, b.w};
  short h8[8], m8[8];
#pragma unroll
  for (int e = 0; e < 8; ++e) {
    __hip_bfloat16 h = __float2bfloat16(v[e]);
    float hf = __bfloat162float(h);
    __hip_bfloat16 m = __float2bfloat16(v[e] - hf);
    h8[e] = *(short*)&h;
    m8[e] = *(short*)&m;
  }
  *(short8*)(dh + (size_t)t * 8) = *(short8*)h8;
  *(short8*)(dm + (size_t)t * 8) = *(short8*)m8;
}

__global__ __launch_bounds__(256)
void pack_weights(const float* __restrict__ W1, const float* __restrict__ W2,
                  const float* __restrict__ W3,
                  short* w1h, short* w1m, short* w2h, short* w2m,
                  short* w3h, short* w3m) {
  const int b = blockIdx.x;
  const int tid = threadIdx.x;
  if (b < 64)       pack8(W1, w1h, w1m, b * 256 + tid, 256, 3);
  else if (b < 128) pack8(W2, w2h, w2m, (b - 64) * 256 + tid, 512, 4);
  else              pack8(W3, w3h, w3m, (b - 128) * 256 + tid, 256, 3);
}

// ---------------- MFMA GEMM: C[M,N] = act(A[M,K] @ B[N,K]^T + bias) ----------------
// 64-row x (32*JT)-col blocks, 4 waves (2x2), wave = 2 i-tiles x JT j-tiles.
// AXREG (gemm1 only): block prologue loads its 64 raw x-rows COALESCED into an
// LDS fp32 buffer (stride 257 -> <=2-way bank aliasing), each wave converts all
// KSTEPS of its A-fragments (hi/mid) into registers once; K-loop stages B only.
// Otherwise A comes pre-packed via global_load_lds DMA (double-buffered).
// Split product: AhBh + AhBm + AmBh (dropped term <= 2^-18 relative).
// MODE 1: tanh + split-pack (hi+mid) epilogue for the next gemm.
// MODE 2: final layer — zero `rz`, write fp32 Cout, row norms in-block,
//         export invn[], write NORMALIZED hi-only pack dh (= vph for gram).
template<int KSTEPS, int JT, int MODE, bool AXREG>
__global__ __launch_bounds__(256, 2)
void mfma_gemm(const float* __restrict__ Araw,
               const short* __restrict__ pAh, const short* __restrict__ pAm,
               const short* __restrict__ pBh, const short* __restrict__ pBm,
               const float* __restrict__ bias, float* __restrict__ Cout,
               short* __restrict__ dh, short* __restrict__ dm, int N,
               float* __restrict__ rz, float* __restrict__ invng) {
  constexpr int ITB = 4;                   // i-tiles per block (64 rows)
  constexpr int BTJ = 2 * JT;              // B tiles per block
  constexpr int NITEMS = (AXREG ? 0 : 2 * ITB) + 2 * BTJ;
  constexpr int PER_WAVE = NITEMS / 4;
  constexpr int WCOL = 16 * JT + 4;        // padded wbuf row stride
  constexpr int XP = 257;                  // xs row stride (floats)
  union SM {
    float xs[AXREG ? 64 * XP : 1];         // prologue x buffer (AXREG only)
    struct {
      short Ah[2][(AXREG ? 1 : ITB) * 512];
      short Am[2][(AXREG ? 1 : ITB) * 512];
      short Bh[2][BTJ * 512];
      short Bm[2][BTJ * 512];
    } st;
    float wbuf[4 * 32 * WCOL];
  };
  __shared__ __align__(16) SM sm;
  __shared__ float nsum[2][64];
  __shared__ float invb[64];

  const int tid = threadIdx.x;
  const int wave = tid >> 6, lane = tid & 63;
  const int wi = wave >> 1, wj = wave & 1;
  const int rr = lane & 15, gg = lane >> 4;
  const int bIt0 = blockIdx.x * ITB;
  const int bJt0 = blockIdx.y * BTJ;

  if constexpr (MODE == 2) {
    // zero the 64 res rows this block owns (res poisoned 0xAA by harness)
    float4* rz4 = (float4*)(rz + (size_t)blockIdx.x * 64 * 64);
#pragma unroll
    for (int u = 0; u < 4; ++u)
      rz4[u * 256 + tid] = make_float4(0.f, 0.f, 0.f, 0.f);
  }

  // ---- AXREG prologue: coalesced x -> LDS -> in-register A-frags ----
  short8 Axh[AXREG ? 2 : 1][AXREG ? KSTEPS : 1];
  short8 Axm[AXREG ? 2 : 1][AXREG ? KSTEPS : 1];
  if constexpr (AXREG) {
    constexpr int K = KSTEPS * 32;
#pragma unroll
    for (int u = 0; u < 16; ++u) {         // 64 rows x 64 float4 / 256 thr
      const int f = u * 256 + tid;
      const int row = f >> 6, c4 = f & 63;
      *(float4*)&sm.xs[row * XP + c4 * 4] =
          *(const float4*)(Araw + (size_t)(bIt0 * 16 + row) * K + c4 * 4);
    }
    __syncthreads();
#pragma unroll
    for (int it = 0; it < 2; ++it) {
      const int row = (wi * 2 + it) * 16 + rr;
#pragma unroll
      for (int q = 0; q < KSTEPS; ++q) {
        const float* p = &sm.xs[row * XP + q * 32 + gg * 8];
        float4 a = *(const float4*)p;
        float4 b = *(const float4*)(p + 4);
        float v[8] = {a.x, a.y, a.z, a.w, b.x, b.y, b.z, b.w};
        short h8[8], m8[8];
#pragma unroll
        for (int e = 0; e < 8; ++e) {
          __hip_bfloat16 h = __float2bfloat16(v[e]);
          float hf = __bfloat162float(h);
          __hip_bfloat16 m = __float2bfloat16(v[e] - hf);
          h8[e] = *(short*)&h;
          m8[e] = *(short*)&m;
        }
        Axh[it][q] = *(short8*)h8;
        Axm[it][q] = *(short8*)m8;
      }
    }
    __syncthreads();                       // xs dead; union region -> B staging
  }

  auto stage = [&](int q, int bf) {
#pragma unroll
    for (int u = 0; u < PER_WAVE; ++u) {
      const int item = wave * PER_WAVE + u;   // wave-uniform
      const short* src;
      short* dst;
      if (!AXREG && item < 2 * ITB) {
        const int t = item >> 1;
        const int m = item & 1;
        src = (m ? pAm : pAh) + ((size_t)(bIt0 + t) * KSTEPS + q) * 512;
        dst = (m ? sm.st.Am : sm.st.Ah)[bf] + t * 512;
      } else {
        const int e = item - (AXREG ? 0 : 2 * ITB);
        const int t = e >> 1;
        const int m = e & 1;
        src = (m ? pBm : pBh) + ((size_t)(bJt0 + t) * KSTEPS + q) * 512;
        dst = (m ? sm.st.Bm : sm.st.Bh)[bf] + t * 512;
      }
      __builtin_amdgcn_global_load_lds(
          (const __attribute__((address_space(1))) void*)(src + lane * 8),
          (__attribute__((address_space(3))) void*)dst, 16, 0, 0);
    }
  };

  f32x4 acc[2][JT];
#pragma unroll
  for (int a = 0; a < 2; ++a)
#pragma unroll
    for (int b = 0; b < JT; ++b) acc[a][b] = (f32x4){0.f, 0.f, 0.f, 0.f};

  stage(0, 0);
#pragma unroll
  for (int q = 0; q < KSTEPS; ++q) {
    __syncthreads();                       // buf q visible; prev reads drained
    if (q + 1 < KSTEPS) stage(q + 1, (q + 1) & 1);
    const int bf = q & 1;
    short8 Ah[2], Am[2];
#pragma unroll
    for (int it = 0; it < 2; ++it) {
      if constexpr (AXREG) {
        Ah[it] = Axh[it][q];
        Am[it] = Axm[it][q];
      } else {
        Ah[it] = *(const short8*)(sm.st.Ah[bf] + (wi * 2 + it) * 512 + lane * 8);
        Am[it] = *(const short8*)(sm.st.Am[bf] + (wi * 2 + it) * 512 + lane * 8);
      }
    }
    short8 Bh[JT], Bm[JT];
#pragma unroll
    for (int jt = 0; jt < JT; ++jt) {
      Bh[jt] = *(const short8*)(sm.st.Bh[bf] + (wj * JT + jt) * 512 + lane * 8);
      Bm[jt] = *(const short8*)(sm.st.Bm[bf] + (wj * JT + jt) * 512 + lane * 8);
    }
#pragma unroll
    for (int it = 0; it < 2; ++it)
#pragma unroll
      for (int jt = 0; jt < JT; ++jt) {
        acc[it][jt] = __builtin_amdgcn_mfma_f32_16x16x32_bf16(Ah[it], Bh[jt], acc[it][jt], 0, 0, 0);
        acc[it][jt] = __builtin_amdgcn_mfma_f32_16x16x32_bf16(Ah[it], Bm[jt], acc[it][jt], 0, 0, 0);
        acc[it][jt] = __builtin_amdgcn_mfma_f32_16x16x32_bf16(Am[it], Bh[jt], acc[it][jt], 0, 0, 0);
      }
  }
  __syncthreads();   // staging dead; union region becomes wbuf

  float bv[JT];
#pragma unroll
  for (int jt = 0; jt < JT; ++jt)
    bv[jt] = bias[(bJt0 + wj * JT + jt) * 16 + rr];

  // C/D layout: col = lane&15, row = (lane>>4)*4 + r
  if constexpr (MODE == 1) {
#pragma unroll
    for (int it = 0; it < 2; ++it)
#pragma unroll
      for (int jt = 0; jt < JT; ++jt)
#pragma unroll
        for (int r = 0; r < 4; ++r) {
          const float val = tanhf(acc[it][jt][r] + bv[jt]);
          const int row_l = it * 16 + gg * 4 + r;
          const int col_l = jt * 16 + rr;
          sm.wbuf[(wave * 32 + row_l) * WCOL + col_l] = val;
        }
    __syncthreads();
  } else {
#pragma unroll
    for (int it = 0; it < 2; ++it)
#pragma unroll
      for (int r = 0; r < 4; ++r) {
        float sq = 0.f;
        const int row_l = it * 16 + gg * 4 + r;
#pragma unroll
        for (int jt = 0; jt < JT; ++jt) {
          const float val = acc[it][jt][r] + bv[jt];
          const int col_l = jt * 16 + rr;
          sm.wbuf[(wave * 32 + row_l) * WCOL + col_l] = val;
          const int row = (bIt0 + wi * 2 + it) * 16 + gg * 4 + r;
          Cout[(size_t)row * N + wj * (16 * JT) + col_l] = val;
          sq = fmaf(val, val, sq);
        }
#pragma unroll
        for (int m = 1; m < 16; m <<= 1) sq += __shfl_xor(sq, m, 64);
        if (rr == 0) nsum[wj][wi * 32 + row_l] = sq;
      }
    __syncthreads();
    if (tid < 64) {
      const float iv = 1.0f / (sqrtf(nsum[0][tid] + nsum[1][tid]) + EPSF);
      invb[tid] = iv;
      invng[blockIdx.x * 64 + tid] = iv;
    }
    __syncthreads();
  }

  // pack epilogue: wbuf -> fragment-major (MODE 1: hi+mid; MODE 2: normalized hi)
  constexpr int QLMAX = (JT >= 2) ? (JT / 2) : 1;
#pragma unroll
  for (int itl = 0; itl < 2; ++itl)
#pragma unroll
    for (int ql = 0; ql < QLMAX; ++ql) {
      const int row_l = itl * 16 + rr;                   // [0,32)
      const int kl = ql * 32 + gg * 8;
      const float* wp = &sm.wbuf[(wave * 32 + row_l) * WCOL + kl];
      const float scale = (MODE == 2) ? invb[wi * 32 + row_l] : 1.0f;
      float4 a = *(const float4*)wp;
      float4 b = *(const float4*)(wp + 4);
      float v[8] = {a.x, a.y, a.z, a.w, b.x, b.y, b.z, b.w};
      short h8[8], m8[8];
#pragma unroll
      for (int e = 0; e < 8; ++e) {
        const float sv = v[e] * scale;
        __hip_bfloat16 h = __float2bfloat16(sv);
        h8[e] = *(short*)&h;
        if constexpr (MODE == 1) {
          float hf = __bfloat162float(h);
          __hip_bfloat16 m = __float2bfloat16(sv - hf);
          m8[e] = *(short*)&m;
        }
      }
      const int ItG = bIt0 + wi * 2 + itl;
      const int qG = (((bJt0 + wj * JT) * 16) + ql * 32) >> 5;
      const size_t off = ((size_t)(ItG * (N >> 5) + qG) * 64 + lane) * 8;
      *(short8*)(dh + off) = *(short8*)h8;
      if constexpr (MODE == 1) *(short8*)(dm + off) = *(short8*)m8;
    }
}

// ---------------- MFMA Gram (hh-only) + guard-band + exact recheck ----------------
#define JSPLIT 8
#define CT 8                                 // j-tiles per chunk (128 j-rows)
#define NCHUNK (B_ROWS / JSPLIT / 16 / CT)   // 8

__global__ __launch_bounds__(256, 2)
void gram_accum(const short* __restrict__ vph, const float* __restrict__ out,
                const float* __restrict__ invn, float* __restrict__ res) {
  __shared__ __align__(16) short lh[2][CT * 1024];   // 2 x 16 KB (hi only)
  const int tid = threadIdx.x;
  const int wave = tid >> 6;
  const int lane = tid & 63;
  const int i0 = blockIdx.x * 128;                   // 8 i-tiles per block
  const int jbase = blockIdx.y * (B_ROWS / JSPLIT);  // 1024 j-rows

  short8 Ah[8][2];
#pragma unroll
  for (int it = 0; it < 8; ++it) {
    const int It = (i0 >> 4) + it;
#pragma unroll
    for (int q = 0; q < 2; ++q)
      Ah[it][q] = *(const short8*)(vph + (size_t)It * 1024 + q * 512 + lane * 8);
  }

  auto stage = [&](int c, int bf) {
    const size_t base = ((size_t)(jbase >> 4) + c * CT) * 1024;
#pragma unroll
    for (int u = 0; u < 4; ++u) {
      const int item = wave * 4 + u;   // 0..15, wave-uniform
      const short* src = vph + base + item * 512;
      short* dst = lh[bf] + item * 512;
      __builtin_amdgcn_global_load_lds(
          (const __attribute__((address_space(1))) void*)(src + lane * 8),
          (__attribute__((address_space(3))) void*)dst, 16, 0, 0);
    }
  };

  stage(0, 0);
  for (int c = 0; c < NCHUNK; ++c) {
    __syncthreads();
    if (c + 1 < NCHUNK) stage(c + 1, (c + 1) & 1);
    const int bf = c & 1;
#pragma unroll
    for (int t = 0; t < 2; ++t) {
      const int jt = wave * 2 + t;
      const int j0 = jbase + (c * CT + jt) * 16;
      short8 Bh0 = *(const short8*)(lh[bf] + jt * 1024 + lane * 8);
      short8 Bh1 = *(const short8*)(lh[bf] + jt * 1024 + 512 + lane * 8);
      f32x4 g[8];
#pragma unroll
      for (int it = 0; it < 8; ++it) g[it] = (f32x4){0.f, 0.f, 0.f, 0.f};
#pragma unroll
      for (int it = 0; it < 8; ++it) g[it] = __builtin_amdgcn_mfma_f32_16x16x32_bf16(Ah[it][0], Bh0, g[it], 0, 0, 0);
#pragma unroll
      for (int it = 0; it < 8; ++it) g[it] = __builtin_amdgcn_mfma_f32_16x16x32_bf16(Ah[it][1], Bh1, g[it], 0, 0, 0);
#pragma unroll
      for (int it = 0; it < 8; ++it) {
        const float m01 = fmaxf(fabsf(g[it][0]), fabsf(g[it][1]));
        const float m23 = fmaxf(fabsf(g[it][2]), fabsf(g[it][3]));
        if (fmaxf(m01, m23) >= GUARD) {
          const int j = j0 + (lane & 15);
          const float ivj = invn[j];
          const float* __restrict__ oj = out + (size_t)j * D_OUT;
#pragma unroll
          for (int r = 0; r < 4; ++r) {
            if (fabsf(g[it][r]) >= GUARD) {
              const int i = i0 + it * 16 + (lane >> 4) * 4 + r;
              if (i != j) {
                const float* __restrict__ oi = out + (size_t)i * D_OUT;
                float d = 0.f;
                for (int k = 0; k < D_OUT; k += 4) {
                  float4 a = *(const float4*)(oi + k);
                  float4 b = *(const float4*)(oj + k);
                  d = fmaf(a.x, b.x, d); d = fmaf(a.y, b.y, d);
                  d = fmaf(a.z, b.z, d); d = fmaf(a.w, b.w, d);
                }
                const float nd = d * invn[i] * ivj;
                if (nd * nd >= THRESH) {
                  float* __restrict__ ri = res + (size_t)i * D_OUT;
                  for (int k = 0; k < D_OUT; ++k) atomicAdd(&ri[k], oj[k]);
                }
              }
            }
          }
        }
      }
    }
  }
}

// ---------------- launch ----------------
#define MB (1024 * 1024)

extern "C" void kernel_launch(void* const* d_in, const int* in_sizes, int n_in,
                              void* d_out, int out_size, void* d_ws, size_t ws_size,
                              hipStream_t stream) {
  const float* x  = (const float*)d_in[0];
  const float* W1 = (const float*)d_in[1];
  const float* b1 = (const float*)d_in[2];
  const float* W2 = (const float*)d_in[3];
  const float* b2 = (const float*)d_in[4];
  const float* W3 = (const float*)d_in[5];
  const float* b3 = (const float*)d_in[6];
  float* res = (float*)d_out;

  char* ws = (char*)d_ws;
  // h2h/h2m at [0,8) MB; h1h/h1m at [8,24) MB; out/vph/invn reuse [8,16)
  // after h1 is dead (consumed by gemm2 before gemm3 writes out).
  short* h2h = (short*)(ws + 0 * MB);
  short* h2m = (short*)(ws + 4 * MB);
  short* h1h = (short*)(ws + 8 * MB);
  short* h1m = (short*)(ws + 16 * MB);
  float* out  = (float*)(ws + 8 * MB);
  short* vph  = (short*)(ws + 11 * MB);
  float* invn = (float*)(ws + 12 * MB);
  // packed weights
  short* w1h = (short*)(ws + 24 * MB);
  short* w1m = (short*)(ws + 24 * MB + 256 * 1024);
  short* w2h = (short*)(ws + 24 * MB + 512 * 1024);
  short* w2m = (short*)(ws + 24 * MB + 768 * 1024);
  short* w3h = (short*)(ws + 25 * MB);
  short* w3m = (short*)(ws + 25 * MB + 32 * 1024);

  pack_weights<<<136, 256, 0, stream>>>(W1, W2, W3, w1h, w1m, w2h, w2m, w3h, w3m);
  // gemm1: raw x (in-register A-frags) @ W1^T(packed) -> tanh -> packed h1 (N=512)
  mfma_gemm<8, 4, 1, true><<<dim3(128, 4), 256, 0, stream>>>(
      x, nullptr, nullptr, w1h, w1m, b1, nullptr, h1h, h1m, H1_DIM, nullptr, nullptr);
  // gemm2: packed h1 @ W2^T(packed) -> tanh -> packed h2 (N=256)
  mfma_gemm<16, 2, 1, false><<<dim3(128, 4), 256, 0, stream>>>(
      nullptr, h1h, h1m, w2h, w2m, b2, nullptr, h2h, h2m, H2_DIM, nullptr, nullptr);
  // gemm3: packed h2 @ W3^T(packed) + b -> fp32 out + invn + normalized hi pack; zeros res
  mfma_gemm<8, 2, 2, false><<<dim3(128, 1), 256, 0, stream>>>(
      nullptr, h2h, h2m, w3h, w3m, b3, out, vph, nullptr, D_OUT, res, invn);
  gram_accum<<<dim3(B_ROWS / 128, JSPLIT), 256, 0, stream>>>(vph, out, invn, res);
}